// Round 3
// baseline (6814.708 us; speedup 1.0000x reference)
//
#include <hip/hip_runtime.h>
#include <hip/hip_bf16.h>

// Problem constants
#define HH 56
#define WWD 56
#define WIN 7
#define SHIFT 3
#define HEADS 8
#define NTOK 49        // WIN*WIN
#define NW 64          // (56/7)^2
#define CDIM 256
#define DH 32          // CDIM/HEADS
#define MROWS 100352   // B*nW*NTOK = 2048*49
#define SCALE_Q 0.17677669529663687f

typedef float floatx4 __attribute__((ext_vector_type(4)));
typedef __bf16 bf16x8 __attribute__((ext_vector_type(8)));

__device__ __forceinline__ float wave_sum(float v) {
#pragma unroll
    for (int m = 1; m < 64; m <<= 1) v += __shfl_xor(v, m);
    return v;
}

__device__ __forceinline__ float b2f(unsigned short u) {
    union { unsigned v; float f; } x; x.v = ((unsigned)u) << 16; return x.f;
}
__device__ __forceinline__ float u2f_lo(unsigned u) {
    union { unsigned v; float f; } x; x.v = u << 16; return x.f;
}
__device__ __forceinline__ float u2f_hi(unsigned u) {
    union { unsigned v; float f; } x; x.v = u & 0xffff0000u; return x.f;
}

__device__ __forceinline__ void glds16(const void* g, void* l) {
    __builtin_amdgcn_global_load_lds(
        (const __attribute__((address_space(1))) void*)g,
        (__attribute__((address_space(3))) void*)l, 16, 0, 0);
}

// ---------------------------------------------------------------------------
// Weight fp32 -> bf16 conversion
__global__ __launch_bounds__(256) void convert_weights_kernel(
    const float* __restrict__ qkv_w, const float* __restrict__ proj_w,
    const float* __restrict__ fc1_w, const float* __restrict__ fc2_w,
    __hip_bfloat16* __restrict__ dst)
{
    int i = blockIdx.x * 256 + threadIdx.x;
    float v;
    if (i < 196608)       v = qkv_w[i];
    else if (i < 262144)  v = proj_w[i - 196608];
    else if (i < 524288)  v = fc1_w[i - 262144];
    else                  v = fc2_w[i - 524288];
    dst[i] = __float2bfloat16(v);
}

// ---------------------------------------------------------------------------
// LayerNorm; SHIFTED=true also applies roll(-3,-3) + window partition scatter.
template <bool SHIFTED>
__global__ __launch_bounds__(256) void ln_kernel(
    const float* __restrict__ x, const float* __restrict__ g,
    const float* __restrict__ bb, __hip_bfloat16* __restrict__ out)
{
    const int tok  = blockIdx.x * 4 + (threadIdx.x >> 6);
    const int lane = threadIdx.x & 63;
    const int c    = lane * 4;

    float4 v = *reinterpret_cast<const float4*>(x + (size_t)tok * CDIM + c);
    float s = v.x + v.y + v.z + v.w;
    s = wave_sum(s);
    const float mean = s * (1.0f / 256.0f);
    float d0 = v.x - mean, d1 = v.y - mean, d2 = v.z - mean, d3 = v.w - mean;
    float sq = d0 * d0 + d1 * d1 + d2 * d2 + d3 * d3;
    sq = wave_sum(sq);
    const float rstd = rsqrtf(sq * (1.0f / 256.0f) + 1e-5f);

    float4 gv = *reinterpret_cast<const float4*>(g + c);
    float4 bv = *reinterpret_cast<const float4*>(bb + c);

    union { __hip_bfloat16 h[4]; uint2 u; } pk;
    pk.h[0] = __float2bfloat16(d0 * rstd * gv.x + bv.x);
    pk.h[1] = __float2bfloat16(d1 * rstd * gv.y + bv.y);
    pk.h[2] = __float2bfloat16(d2 * rstd * gv.z + bv.z);
    pk.h[3] = __float2bfloat16(d3 * rstd * gv.w + bv.w);

    size_t oidx;
    if (SHIFTED) {
        int b = tok / 3136;
        int l = tok - b * 3136;
        int h = l / WWD, w = l - (l / WWD) * WWD;
        int hp = h - SHIFT; if (hp < 0) hp += HH;
        int wp = w - SHIFT; if (wp < 0) wp += WWD;
        int bwin = b * NW + (hp / WIN) * 8 + (wp / WIN);
        int n = (hp % WIN) * WIN + (wp % WIN);
        oidx = ((size_t)bwin * NTOK + n) * CDIM + c;
    } else {
        oidx = (size_t)tok * CDIM + c;
    }
    *reinterpret_cast<uint2*>(out + oidx) = pk.u;
}

// ---------------------------------------------------------------------------
// bf16 MFMA GEMM v2 (m97 structure): C[M,N] = A[M,K]*Wt[N,K]^T.
// 128x128 tile, BK=32, global_load_lds(16B) staging, XOR-swizzled LDS chunks.
// Each of 4 waves computes 64x64 via 4x4 mfma_16x16x32_bf16.
template <int MODE>
__global__ __launch_bounds__(256) void gemm_kernel(
    const __hip_bfloat16* __restrict__ A,
    const __hip_bfloat16* __restrict__ Wt,
    const float* __restrict__ bias,
    void* __restrict__ outv,
    const float* __restrict__ aux,
    int M, int Nn, int K)
{
    __shared__ __hip_bfloat16 As[128 * 32];   // 8KB, row-major, 16B chunks swizzled
    __shared__ __hip_bfloat16 Bs[128 * 32];

    const int t = threadIdx.x;
    const int wave = t >> 6, lane = t & 63;
    const int m0 = blockIdx.y * 128, n0 = blockIdx.x * 128;
    const int wr = (wave >> 1) * 64;
    const int wc = (wave & 1) * 64;

    floatx4 acc[4][4] = {};

    // staging: 512 chunks of 16B per tile; thread t handles chunks c0, c0+256
    const int c0 = wave * 64 + lane;
    const int c1 = 256 + c0;
    const int r0 = c0 >> 2, p0 = c0 & 3, g0 = p0 ^ ((r0 >> 1) & 3);
    const int r1 = c1 >> 2, p1 = c1 & 3, g1 = p1 ^ ((r1 >> 1) & 3);
    const __hip_bfloat16* gA0 = A  + (size_t)(m0 + r0) * K + g0 * 8;
    const __hip_bfloat16* gA1 = A  + (size_t)(m0 + r1) * K + g1 * 8;
    const __hip_bfloat16* gB0 = Wt + (size_t)(n0 + r0) * K + g0 * 8;
    const __hip_bfloat16* gB1 = Wt + (size_t)(n0 + r1) * K + g1 * 8;
    // wave-uniform LDS bases (HW adds lane*16)
    const int base0 = (wave * 64) * 8;        // elements
    const int base1 = (256 + wave * 64) * 8;

    const int fm = lane & 15;          // fragment row/col within 16
    const int g4 = lane >> 4;          // k-chunk index (8 elems)

    for (int k0 = 0; k0 < K; k0 += 32) {
        __syncthreads();               // previous iter's consumers done
        glds16(gA0 + k0, As + base0);
        glds16(gA1 + k0, As + base1);
        glds16(gB0 + k0, Bs + base0);
        glds16(gB1 + k0, Bs + base1);
        __syncthreads();               // drains vmcnt(0): data visible

        bf16x8 af[4], bfr[4];
#pragma unroll
        for (int mt = 0; mt < 4; ++mt) {
            const int ml = wr + mt * 16 + fm;
            af[mt] = *reinterpret_cast<const bf16x8*>(
                As + ml * 32 + ((g4 ^ ((ml >> 1) & 3)) * 8));
            const int nl = wc + mt * 16 + fm;
            bfr[mt] = *reinterpret_cast<const bf16x8*>(
                Bs + nl * 32 + ((g4 ^ ((nl >> 1) & 3)) * 8));
        }
#pragma unroll
        for (int mt = 0; mt < 4; ++mt)
#pragma unroll
            for (int nt = 0; nt < 4; ++nt)
                acc[mt][nt] = __builtin_amdgcn_mfma_f32_16x16x32_bf16(
                    af[mt], bfr[nt], acc[mt][nt], 0, 0, 0);
    }

    // Epilogue. D mapping: col = lane&15, row = (lane>>4)*4 + reg.
    float bv[4];
#pragma unroll
    for (int nt = 0; nt < 4; ++nt) bv[nt] = bias[n0 + wc + nt * 16 + fm];

#pragma unroll
    for (int mt = 0; mt < 4; ++mt) {
#pragma unroll
        for (int r = 0; r < 4; ++r) {
            const int m_g = m0 + wr + mt * 16 + g4 * 4 + r;
            size_t row_idx = 0;
            if (MODE == 1) {
                int bwin = m_g / NTOK;
                int ntok = m_g - bwin * NTOK;
                int b = bwin >> 6, wi = bwin & 63;
                int rr = ntok / WIN, cc = ntok - rr * WIN;
                int hp = (wi >> 3) * WIN + rr;
                int wp = (wi & 7) * WIN + cc;
                int h = hp + SHIFT; if (h >= HH) h -= HH;
                int w = wp + SHIFT; if (w >= WWD) w -= WWD;
                row_idx = ((size_t)b * 3136 + h * WWD + w) * CDIM;
            }
#pragma unroll
            for (int nt = 0; nt < 4; ++nt) {
                const int n_g = n0 + wc + nt * 16 + fm;
                float val = acc[mt][nt][r] + bv[nt];
                if (MODE == 0) {
                    if (n_g < 256) val *= SCALE_Q;
                    reinterpret_cast<__hip_bfloat16*>(outv)[(size_t)m_g * Nn + n_g] =
                        __float2bfloat16(val);
                } else if (MODE == 2) {
                    float gl = 0.5f * val * (1.0f + erff(val * 0.70710678118654752f));
                    reinterpret_cast<__hip_bfloat16*>(outv)[(size_t)m_g * Nn + n_g] =
                        __float2bfloat16(gl);
                } else if (MODE == 3) {
                    size_t idx = (size_t)m_g * CDIM + n_g;
                    reinterpret_cast<float*>(outv)[idx] = aux[idx] + val;
                } else {
                    size_t idx = row_idx + n_g;
                    reinterpret_cast<float*>(outv)[idx] = aux[idx] + val;
                }
            }
        }
    }
}

// ---------------------------------------------------------------------------
// Attention v3: lane = query row, serial key loop. K/V staged as bf16 in LDS
// (halves LDS traffic + footprint); unpack at use. launch_bounds(256,4) to
// force 4 waves/SIMD occupancy.
__global__ __launch_bounds__(256, 4) void attn_kernel(
    const __hip_bfloat16* __restrict__ qkv,   // (B_,49,768) bf16, q pre-scaled
    const float* __restrict__ rpb_table,      // (169,8)
    const float* __restrict__ sal_fg,         // (B_,49,49): row 0 = key mask
    __hip_bfloat16* __restrict__ o)           // (B_,49,256)
{
    __shared__ unsigned ksu[4][NTOK * 16];    // 49 rows x 32 bf16 (16 uints)
    __shared__ unsigned vsu[4][NTOK * 16];
    __shared__ float rpb_l[4][169];

    const int t = threadIdx.x;
    const int wave = t >> 6, lane = t & 63;
    const int b_ = blockIdx.x >> 1;
    const int h = ((blockIdx.x & 1) << 2) | wave;

    unsigned* ksw = ksu[wave];
    unsigned* vsw = vsu[wave];
    float* rpbw = rpb_l[wave];

    const unsigned short* qkv_u = reinterpret_cast<const unsigned short*>(qkv);
    const size_t base = (size_t)b_ * (NTOK * 768) + h * DH;

    // Stage K,V bf16 -> LDS: 392 uint4 chunks (wave-local, no barrier)
#pragma unroll
    for (int it = 0; it < 7; ++it) {
        int c = it * 64 + lane;
        if (c < 392) {
            int kv = (c >= 196);
            int cc = c - (kv ? 196 : 0);
            int row = cc >> 2, p = cc & 3;
            const uint4 d = *reinterpret_cast<const uint4*>(
                qkv_u + base + row * 768 + (kv ? 512 : 256) + p * 8);
            unsigned* dst = (kv ? vsw : ksw) + row * 16 + p * 4;
            *reinterpret_cast<uint4*>(dst) = d;
        }
    }
#pragma unroll
    for (int it = 0; it < 3; ++it) {
        int idx = it * 64 + lane;
        if (idx < 169) rpbw[idx] = rpb_table[idx * 8 + h];
    }

    // q row for this lane (fp32 registers)
    const int r = (lane < NTOK) ? lane : 48;
    float qf[32];
#pragma unroll
    for (int cc4 = 0; cc4 < 8; ++cc4) {
        ushort4 qq = *reinterpret_cast<const ushort4*>(
            qkv_u + base + (size_t)r * 768 + cc4 * 4);
        qf[cc4 * 4 + 0] = b2f(qq.x);
        qf[cc4 * 4 + 1] = b2f(qq.y);
        qf[cc4 * 4 + 2] = b2f(qq.z);
        qf[cc4 * 4 + 3] = b2f(qq.w);
    }

    float sfv = (lane < NTOK) ? sal_fg[(size_t)b_ * (NTOK * NTOK) + lane] : -100.f;
    const unsigned long long fgmask = __ballot(sfv == 0.0f);

    const int wr_ = (b_ & 63) >> 3, wc_ = (b_ & 63) & 7;
    const int rr = r / 7, rc = r - (r / 7) * 7;
    const int rreg = ((wr_ == 7) ? ((rr < 4) ? 1 : 2) : 0) * 3
                   + ((wc_ == 7) ? ((rc < 4) ? 1 : 2) : 0);
    const int rpb_base = rr * 13 + rc + 84;   // +84 = (+6)*13 + 6

#define QKFMA(u, i0) { \
    acc0 = fmaf(qf[i0], u2f_lo(u), acc0); \
    acc1 = fmaf(qf[(i0) + 1], u2f_hi(u), acc1); }

    // ---- pass 1a: logits + running maxes
    float sreg[49];
    float m0 = -1e30f, m1 = -1e30f, m2 = -1e30f;
#pragma unroll
    for (int j = 0; j < 49; ++j) {
        const int jr = j / 7, jc = j - (j / 7) * 7;
        const uint4 ka = *reinterpret_cast<const uint4*>(ksw + j * 16);
        const uint4 kb = *reinterpret_cast<const uint4*>(ksw + j * 16 + 4);
        const uint4 kc = *reinterpret_cast<const uint4*>(ksw + j * 16 + 8);
        const uint4 kd = *reinterpret_cast<const uint4*>(ksw + j * 16 + 12);
        float acc0 = 0.f, acc1 = 0.f;
        QKFMA(ka.x, 0)  QKFMA(ka.y, 2)  QKFMA(ka.z, 4)  QKFMA(ka.w, 6)
        QKFMA(kb.x, 8)  QKFMA(kb.y, 10) QKFMA(kb.z, 12) QKFMA(kb.w, 14)
        QKFMA(kc.x, 16) QKFMA(kc.y, 18) QKFMA(kc.z, 20) QKFMA(kc.w, 22)
        QKFMA(kd.x, 24) QKFMA(kd.y, 26) QKFMA(kd.z, 28) QKFMA(kd.w, 30)
        float s = acc0 + acc1;
        s += rpbw[rpb_base - jr * 13 - jc];
        const int jreg = ((wr_ == 7) ? ((jr < 4) ? 1 : 2) : 0) * 3
                       + ((wc_ == 7) ? ((jc < 4) ? 1 : 2) : 0);
        s += (rreg == jreg) ? 0.f : -100.f;
        const float sf = ((fgmask >> j) & 1ULL) ? 0.f : -100.f;
        sreg[j] = s;
        m0 = fmaxf(m0, s);
        m1 = fmaxf(m1, s + sf);
        m2 = fmaxf(m2, s - 100.f - sf);
    }

    // ---- pass 1b: denominators
    float S0 = 0.f, S1 = 0.f, S2 = 0.f;
#pragma unroll
    for (int j = 0; j < 49; ++j) {
        const float sf = ((fgmask >> j) & 1ULL) ? 0.f : -100.f;
        S0 += __expf(sreg[j] - m0);
        S1 += __expf(sreg[j] + sf - m1);
        S2 += __expf(sreg[j] - 100.f - sf - m2);
    }
    const float r0 = 1.f / S0, r1 = 1.f / S1, r2 = 1.f / S2;

    // ---- pass 2: combined probabilities + PV
    float oacc[32];
#pragma unroll
    for (int d = 0; d < 32; ++d) oacc[d] = 0.f;
#pragma unroll
    for (int j = 0; j < 49; ++j) {
        const float sf = ((fgmask >> j) & 1ULL) ? 0.f : -100.f;
        const float p = __expf(sreg[j] - m0) * r0
                      + __expf(sreg[j] + sf - m1) * r1
                      - __expf(sreg[j] - 100.f - sf - m2) * r2;
        const uint4 va = *reinterpret_cast<const uint4*>(vsw + j * 16);
        const uint4 vb = *reinterpret_cast<const uint4*>(vsw + j * 16 + 4);
        const uint4 vc = *reinterpret_cast<const uint4*>(vsw + j * 16 + 8);
        const uint4 vd = *reinterpret_cast<const uint4*>(vsw + j * 16 + 12);
#define PVFMA(u, i0) { \
        oacc[i0] = fmaf(p, u2f_lo(u), oacc[i0]); \
        oacc[(i0) + 1] = fmaf(p, u2f_hi(u), oacc[(i0) + 1]); }
        PVFMA(va.x, 0)  PVFMA(va.y, 2)  PVFMA(va.z, 4)  PVFMA(va.w, 6)
        PVFMA(vb.x, 8)  PVFMA(vb.y, 10) PVFMA(vb.z, 12) PVFMA(vb.w, 14)
        PVFMA(vc.x, 16) PVFMA(vc.y, 18) PVFMA(vc.z, 20) PVFMA(vc.w, 22)
        PVFMA(vd.x, 24) PVFMA(vd.y, 26) PVFMA(vd.z, 28) PVFMA(vd.w, 30)
#undef PVFMA
    }

    if (lane < NTOK) {
        __hip_bfloat16 ob[32];
#pragma unroll
        for (int d = 0; d < 32; ++d) ob[d] = __float2bfloat16(oacc[d]);
        __hip_bfloat16* op = o + ((size_t)b_ * NTOK + lane) * CDIM + h * DH;
#pragma unroll
        for (int ii = 0; ii < 4; ++ii)
            reinterpret_cast<int4*>(op)[ii] = reinterpret_cast<const int4*>(ob)[ii];
    }
}

// ---------------------------------------------------------------------------
extern "C" void kernel_launch(void* const* d_in, const int* in_sizes, int n_in,
                              void* d_out, int out_size, void* d_ws, size_t ws_size,
                              hipStream_t stream)
{
    const float* x        = (const float*)d_in[0];
    const float* qkv_w    = (const float*)d_in[1];
    const float* qkv_b    = (const float*)d_in[2];
    const float* rpb_tab  = (const float*)d_in[3];
    const float* proj_w   = (const float*)d_in[4];
    const float* proj_b   = (const float*)d_in[5];
    const float* n1g      = (const float*)d_in[6];
    const float* n1b      = (const float*)d_in[7];
    const float* n2g      = (const float*)d_in[8];
    const float* n2b      = (const float*)d_in[9];
    const float* fc1_w    = (const float*)d_in[10];
    const float* fc1_b    = (const float*)d_in[11];
    const float* fc2_w    = (const float*)d_in[12];
    const float* fc2_b    = (const float*)d_in[13];
    const float* sal_fg   = (const float*)d_in[15];

    char* ws = (char*)d_ws;
    __hip_bfloat16* regA = (__hip_bfloat16*)ws;
    __hip_bfloat16* regB = (__hip_bfloat16*)(ws + 205520896);
    float*          x2   = (float*)(ws + 205520896 + 51380224);
    __hip_bfloat16* wbf  = (__hip_bfloat16*)(ws + 205520896 + 51380224 + 102760448);
    __hip_bfloat16* wqkv  = wbf;
    __hip_bfloat16* wproj = wbf + 196608;
    __hip_bfloat16* wfc1  = wbf + 262144;
    __hip_bfloat16* wfc2  = wbf + 524288;

    convert_weights_kernel<<<3072, 256, 0, stream>>>(qkv_w, proj_w, fc1_w, fc2_w, wbf);

    ln_kernel<true><<<MROWS / 4, 256, 0, stream>>>(x, n1g, n1b, regB);

    gemm_kernel<0><<<dim3(768 / 128, MROWS / 128), 256, 0, stream>>>(
        regB, wqkv, qkv_b, regA, nullptr, MROWS, 768, 256);

    attn_kernel<<<2048 * 2, 256, 0, stream>>>(regA, rpb_tab, sal_fg, regB);

    gemm_kernel<1><<<dim3(256 / 128, MROWS / 128), 256, 0, stream>>>(
        regB, wproj, proj_b, x2, x, MROWS, 256, 256);

    ln_kernel<false><<<MROWS / 4, 256, 0, stream>>>(x2, n2g, n2b, regB);

    gemm_kernel<2><<<dim3(1024 / 128, MROWS / 128), 256, 0, stream>>>(
        regB, wfc1, fc1_b, regA, nullptr, MROWS, 1024, 256);

    gemm_kernel<3><<<dim3(256 / 128, MROWS / 128), 256, 0, stream>>>(
        regA, wfc2, fc2_b, d_out, x2, MROWS, 256, 1024);
}

// Round 4
// 786.303 us; speedup vs baseline: 8.6668x; 8.6668x over previous
//
#include <hip/hip_runtime.h>
#include <hip/hip_bf16.h>

// Problem constants
#define HH 56
#define WWD 56
#define WIN 7
#define SHIFT 3
#define HEADS 8
#define NTOK 49        // WIN*WIN
#define NW 64          // (56/7)^2
#define CDIM 256
#define DH 32          // CDIM/HEADS
#define MROWS 100352   // B*nW*NTOK = 2048*49
#define SCALE_Q 0.17677669529663687f

typedef float floatx4 __attribute__((ext_vector_type(4)));
typedef __bf16 bf16x8 __attribute__((ext_vector_type(8)));

__device__ __forceinline__ float wave_sum(float v) {
#pragma unroll
    for (int m = 1; m < 64; m <<= 1) v += __shfl_xor(v, m);
    return v;
}

__device__ __forceinline__ void glds16(const void* g, void* l) {
    __builtin_amdgcn_global_load_lds(
        (const __attribute__((address_space(1))) void*)g,
        (__attribute__((address_space(3))) void*)l, 16, 0, 0);
}

// ---------------------------------------------------------------------------
// Weight fp32 -> bf16 conversion
__global__ __launch_bounds__(256) void convert_weights_kernel(
    const float* __restrict__ qkv_w, const float* __restrict__ proj_w,
    const float* __restrict__ fc1_w, const float* __restrict__ fc2_w,
    __hip_bfloat16* __restrict__ dst)
{
    int i = blockIdx.x * 256 + threadIdx.x;
    float v;
    if (i < 196608)       v = qkv_w[i];
    else if (i < 262144)  v = proj_w[i - 196608];
    else if (i < 524288)  v = fc1_w[i - 262144];
    else                  v = fc2_w[i - 524288];
    dst[i] = __float2bfloat16(v);
}

// ---------------------------------------------------------------------------
// LayerNorm; SHIFTED=true also applies roll(-3,-3) + window partition scatter.
template <bool SHIFTED>
__global__ __launch_bounds__(256) void ln_kernel(
    const float* __restrict__ x, const float* __restrict__ g,
    const float* __restrict__ bb, __hip_bfloat16* __restrict__ out)
{
    const int tok  = blockIdx.x * 4 + (threadIdx.x >> 6);
    const int lane = threadIdx.x & 63;
    const int c    = lane * 4;

    float4 v = *reinterpret_cast<const float4*>(x + (size_t)tok * CDIM + c);
    float s = v.x + v.y + v.z + v.w;
    s = wave_sum(s);
    const float mean = s * (1.0f / 256.0f);
    float d0 = v.x - mean, d1 = v.y - mean, d2 = v.z - mean, d3 = v.w - mean;
    float sq = d0 * d0 + d1 * d1 + d2 * d2 + d3 * d3;
    sq = wave_sum(sq);
    const float rstd = rsqrtf(sq * (1.0f / 256.0f) + 1e-5f);

    float4 gv = *reinterpret_cast<const float4*>(g + c);
    float4 bv = *reinterpret_cast<const float4*>(bb + c);

    union { __hip_bfloat16 h[4]; uint2 u; } pk;
    pk.h[0] = __float2bfloat16(d0 * rstd * gv.x + bv.x);
    pk.h[1] = __float2bfloat16(d1 * rstd * gv.y + bv.y);
    pk.h[2] = __float2bfloat16(d2 * rstd * gv.z + bv.z);
    pk.h[3] = __float2bfloat16(d3 * rstd * gv.w + bv.w);

    size_t oidx;
    if (SHIFTED) {
        int b = tok / 3136;
        int l = tok - b * 3136;
        int h = l / WWD, w = l - (l / WWD) * WWD;
        int hp = h - SHIFT; if (hp < 0) hp += HH;
        int wp = w - SHIFT; if (wp < 0) wp += WWD;
        int bwin = b * NW + (hp / WIN) * 8 + (wp / WIN);
        int n = (hp % WIN) * WIN + (wp % WIN);
        oidx = ((size_t)bwin * NTOK + n) * CDIM + c;
    } else {
        oidx = (size_t)tok * CDIM + c;
    }
    *reinterpret_cast<uint2*>(out + oidx) = pk.u;
}

// ---------------------------------------------------------------------------
// bf16 MFMA GEMM (m97 structure): 128x128 tile, BK=32, global_load_lds(16B),
// XOR-swizzled LDS chunks. 4 waves x (64x64 via 4x4 mfma_16x16x32_bf16).
template <int MODE>
__global__ __launch_bounds__(256) void gemm_kernel(
    const __hip_bfloat16* __restrict__ A,
    const __hip_bfloat16* __restrict__ Wt,
    const float* __restrict__ bias,
    void* __restrict__ outv,
    const float* __restrict__ aux,
    int M, int Nn, int K)
{
    __shared__ __hip_bfloat16 As[128 * 32];
    __shared__ __hip_bfloat16 Bs[128 * 32];

    const int t = threadIdx.x;
    const int wave = t >> 6, lane = t & 63;
    const int m0 = blockIdx.y * 128, n0 = blockIdx.x * 128;
    const int wr = (wave >> 1) * 64;
    const int wc = (wave & 1) * 64;

    floatx4 acc[4][4] = {};

    const int c0 = wave * 64 + lane;
    const int c1 = 256 + c0;
    const int r0 = c0 >> 2, p0 = c0 & 3, g0 = p0 ^ ((r0 >> 1) & 3);
    const int r1 = c1 >> 2, p1 = c1 & 3, g1 = p1 ^ ((r1 >> 1) & 3);
    const __hip_bfloat16* gA0 = A  + (size_t)(m0 + r0) * K + g0 * 8;
    const __hip_bfloat16* gA1 = A  + (size_t)(m0 + r1) * K + g1 * 8;
    const __hip_bfloat16* gB0 = Wt + (size_t)(n0 + r0) * K + g0 * 8;
    const __hip_bfloat16* gB1 = Wt + (size_t)(n0 + r1) * K + g1 * 8;
    const int base0 = (wave * 64) * 8;
    const int base1 = (256 + wave * 64) * 8;

    const int fm = lane & 15;
    const int g4 = lane >> 4;

    for (int k0 = 0; k0 < K; k0 += 32) {
        __syncthreads();
        glds16(gA0 + k0, As + base0);
        glds16(gA1 + k0, As + base1);
        glds16(gB0 + k0, Bs + base0);
        glds16(gB1 + k0, Bs + base1);
        __syncthreads();

        bf16x8 af[4], bfr[4];
#pragma unroll
        for (int mt = 0; mt < 4; ++mt) {
            const int ml = wr + mt * 16 + fm;
            af[mt] = *reinterpret_cast<const bf16x8*>(
                As + ml * 32 + ((g4 ^ ((ml >> 1) & 3)) * 8));
            const int nl = wc + mt * 16 + fm;
            bfr[mt] = *reinterpret_cast<const bf16x8*>(
                Bs + nl * 32 + ((g4 ^ ((nl >> 1) & 3)) * 8));
        }
#pragma unroll
        for (int mt = 0; mt < 4; ++mt)
#pragma unroll
            for (int nt = 0; nt < 4; ++nt)
                acc[mt][nt] = __builtin_amdgcn_mfma_f32_16x16x32_bf16(
                    af[mt], bfr[nt], acc[mt][nt], 0, 0, 0);
    }

    float bv[4];
#pragma unroll
    for (int nt = 0; nt < 4; ++nt) bv[nt] = bias[n0 + wc + nt * 16 + fm];

#pragma unroll
    for (int mt = 0; mt < 4; ++mt) {
#pragma unroll
        for (int r = 0; r < 4; ++r) {
            const int m_g = m0 + wr + mt * 16 + g4 * 4 + r;
            size_t row_idx = 0;
            if (MODE == 1) {
                int bwin = m_g / NTOK;
                int ntok = m_g - bwin * NTOK;
                int b = bwin >> 6, wi = bwin & 63;
                int rr = ntok / WIN, cc = ntok - rr * WIN;
                int hp = (wi >> 3) * WIN + rr;
                int wp = (wi & 7) * WIN + cc;
                int h = hp + SHIFT; if (h >= HH) h -= HH;
                int w = wp + SHIFT; if (w >= WWD) w -= WWD;
                row_idx = ((size_t)b * 3136 + h * WWD + w) * CDIM;
            }
#pragma unroll
            for (int nt = 0; nt < 4; ++nt) {
                const int n_g = n0 + wc + nt * 16 + fm;
                float val = acc[mt][nt][r] + bv[nt];
                if (MODE == 0) {
                    if (n_g < 256) val *= SCALE_Q;
                    reinterpret_cast<__hip_bfloat16*>(outv)[(size_t)m_g * Nn + n_g] =
                        __float2bfloat16(val);
                } else if (MODE == 2) {
                    float gl = 0.5f * val * (1.0f + erff(val * 0.70710678118654752f));
                    reinterpret_cast<__hip_bfloat16*>(outv)[(size_t)m_g * Nn + n_g] =
                        __float2bfloat16(gl);
                } else if (MODE == 3) {
                    size_t idx = (size_t)m_g * CDIM + n_g;
                    reinterpret_cast<float*>(outv)[idx] = aux[idx] + val;
                } else {
                    size_t idx = row_idx + n_g;
                    reinterpret_cast<float*>(outv)[idx] = aux[idx] + val;
                }
            }
        }
    }
}

// ---------------------------------------------------------------------------
// Attention v4 (MFMA): one wave per (window, head). S^T = K·Q^T via 16 MFMAs
// (M=keys64pad, N=queries64pad, K=32). Softmax over keys = per-lane serial
// reduce over 16 regs + shfl_xor(16,32). P (bf16) and V^T staged in LDS with
// xor-swizzled 16B chunks; PV via 8 MFMAs. Pad keys forced to p=0; pad-query
// rows never stored. No min-wave launch bound (R3 spill lesson).
__global__ __launch_bounds__(256) void attn_kernel(
    const __hip_bfloat16* __restrict__ qkv,   // (B_,49,768) bf16, q pre-scaled
    const float* __restrict__ rpb_table,      // (169,8)
    const float* __restrict__ sal_fg,         // (B_,49,49): row 0 = key mask
    __hip_bfloat16* __restrict__ o)           // (B_,49,256)
{
    __shared__ unsigned short Pl[4][64 * 64];   // [query][key] swizzled, bf16
    __shared__ unsigned short Vt[4][32 * 64];   // [d][key] swizzled, bf16
    __shared__ float rpb_l[4][172];

    const int t = threadIdx.x;
    const int wave = t >> 6, lane = t & 63;
    const int lane15 = lane & 15, g4 = lane >> 4;
    const int b_ = blockIdx.x >> 1;
    const int h = ((blockIdx.x & 1) << 2) | wave;

    unsigned short* Pw = Pl[wave];
    unsigned short* Vw = Vt[wave];
    float* rpbw = rpb_l[wave];

    const unsigned short* qkv_u = reinterpret_cast<const unsigned short*>(qkv);
    const size_t base = (size_t)b_ * (NTOK * 768) + h * DH;

    // ---- stage V^T [d][key] (xor swizzle chunk^(d&7)); zero pad keys 49..63
#pragma unroll
    for (int it = 0; it < 32; ++it) {
        int idx = it * 64 + lane;            // 0..2047
        int key = idx >> 5, d = idx & 31;
        unsigned short v = 0;
        if (key < NTOK) v = qkv_u[base + key * 768 + 512 + d];
        Vw[d * 64 + (((key >> 3) ^ (d & 7)) << 3) + (key & 7)] = v;
    }
#pragma unroll
    for (int it = 0; it < 3; ++it) {
        int i = it * 64 + lane;
        if (i < 169) rpbw[i] = rpb_table[i * 8 + h];
    }
    float sfv = (lane < NTOK) ? sal_fg[(size_t)b_ * (NTOK * NTOK) + lane] : -100.f;
    const unsigned long long fgmask = __ballot(sfv == 0.0f);

    // ---- K,Q fragments straight from global (16B/lane, aligned)
    bf16x8 kf[4], qf[4];
#pragma unroll
    for (int mt = 0; mt < 4; ++mt)
        kf[mt] = *reinterpret_cast<const bf16x8*>(
            qkv_u + base + (size_t)(mt * 16 + lane15) * 768 + 256 + g4 * 8);
#pragma unroll
    for (int nt = 0; nt < 4; ++nt)
        qf[nt] = *reinterpret_cast<const bf16x8*>(
            qkv_u + base + (size_t)(nt * 16 + lane15) * 768 + g4 * 8);

    // ---- S^T[key][query] = K·Q^T
    floatx4 S[4][4] = {};
#pragma unroll
    for (int mt = 0; mt < 4; ++mt)
#pragma unroll
        for (int nt = 0; nt < 4; ++nt)
            S[mt][nt] = __builtin_amdgcn_mfma_f32_16x16x32_bf16(
                kf[mt], qf[nt], S[mt][nt], 0, 0, 0);

    // ---- per-query-column constants
    const int wr_ = (b_ & 63) >> 3, wc_ = (b_ & 63) & 7;
    int qlin[4], qreg[4];
#pragma unroll
    for (int nt = 0; nt < 4; ++nt) {
        int q = nt * 16 + lane15;
        int qr = (q * 147) >> 10, qc = q - qr * 7;
        qlin[nt] = q + 6 * qr + 84;          // qr*13+qc+84
        qreg[nt] = ((wr_ == 7) ? ((qr < 4) ? 1 : 2) : 0) * 3
                 + ((wc_ == 7) ? ((qc < 4) ? 1 : 2) : 0);
    }

    // ---- apply rpb + shift-region mask; pad keys -> -1e30
#pragma unroll
    for (int mt = 0; mt < 4; ++mt)
#pragma unroll
        for (int r = 0; r < 4; ++r) {
            int key = mt * 16 + g4 * 4 + r;
            int kr = (key * 147) >> 10, kc = key - kr * 7;
            int klin = key + 6 * kr;
            int kreg = ((wr_ == 7) ? ((kr < 4) ? 1 : 2) : 0) * 3
                     + ((wc_ == 7) ? ((kc < 4) ? 1 : 2) : 0);
            bool pad = key >= NTOK;
#pragma unroll
            for (int nt = 0; nt < 4; ++nt) {
                int idx = qlin[nt] - klin;
                idx = idx < 0 ? 0 : (idx > 168 ? 168 : idx);
                float s = S[mt][nt][r] + rpbw[idx]
                        + ((qreg[nt] == kreg) ? 0.f : -100.f);
                S[mt][nt][r] = pad ? -1e30f : s;
            }
        }

    // ---- 3-way softmax stats per query column
    float M0[4], M1[4], M2[4], R0[4], R1[4], R2[4];
#pragma unroll
    for (int nt = 0; nt < 4; ++nt) {
        float a0 = -1e30f, a1 = -1e30f, a2 = -1e30f;
#pragma unroll
        for (int mt = 0; mt < 4; ++mt)
#pragma unroll
            for (int r = 0; r < 4; ++r) {
                int key = mt * 16 + g4 * 4 + r;
                float sf = ((fgmask >> key) & 1ULL) ? 0.f : -100.f;
                float s = S[mt][nt][r];
                a0 = fmaxf(a0, s);
                a1 = fmaxf(a1, s + sf);
                a2 = fmaxf(a2, s - 100.f - sf);
            }
        a0 = fmaxf(a0, __shfl_xor(a0, 16)); a0 = fmaxf(a0, __shfl_xor(a0, 32));
        a1 = fmaxf(a1, __shfl_xor(a1, 16)); a1 = fmaxf(a1, __shfl_xor(a1, 32));
        a2 = fmaxf(a2, __shfl_xor(a2, 16)); a2 = fmaxf(a2, __shfl_xor(a2, 32));
        float s0 = 0.f, s1 = 0.f, s2 = 0.f;
#pragma unroll
        for (int mt = 0; mt < 4; ++mt)
#pragma unroll
            for (int r = 0; r < 4; ++r) {
                int key = mt * 16 + g4 * 4 + r;
                float sf = ((fgmask >> key) & 1ULL) ? 0.f : -100.f;
                float s = S[mt][nt][r];
                s0 += __expf(s - a0);
                s1 += __expf(s + sf - a1);
                s2 += __expf(s - 100.f - sf - a2);
            }
        s0 += __shfl_xor(s0, 16); s0 += __shfl_xor(s0, 32);
        s1 += __shfl_xor(s1, 16); s1 += __shfl_xor(s1, 32);
        s2 += __shfl_xor(s2, 16); s2 += __shfl_xor(s2, 32);
        M0[nt] = a0; M1[nt] = a1; M2[nt] = a2;
        R0[nt] = 1.f / s0; R1[nt] = 1.f / s1; R2[nt] = 1.f / s2;
    }

    // ---- combined p -> bf16 -> P LDS (paired b32 stores)
#pragma unroll
    for (int mt = 0; mt < 4; ++mt)
#pragma unroll
        for (int rp = 0; rp < 2; ++rp) {
            int key0 = mt * 16 + g4 * 4 + 2 * rp;
            float sf0 = ((fgmask >> key0) & 1ULL) ? 0.f : -100.f;
            float sf1 = ((fgmask >> (key0 + 1)) & 1ULL) ? 0.f : -100.f;
            int chunk = key0 >> 3;
#pragma unroll
            for (int nt = 0; nt < 4; ++nt) {
                float sA = S[mt][nt][2 * rp];
                float sB = S[mt][nt][2 * rp + 1];
                float pA = __expf(sA - M0[nt]) * R0[nt]
                         + __expf(sA + sf0 - M1[nt]) * R1[nt]
                         - __expf(sA - 100.f - sf0 - M2[nt]) * R2[nt];
                float pB = __expf(sB - M0[nt]) * R0[nt]
                         + __expf(sB + sf1 - M1[nt]) * R1[nt]
                         - __expf(sB - 100.f - sf1 - M2[nt]) * R2[nt];
                union { __hip_bfloat16 hh[2]; unsigned u; } pk;
                pk.hh[0] = __float2bfloat16(pA);
                pk.hh[1] = __float2bfloat16(pB);
                int q = nt * 16 + lane15;
                int addr = q * 64 + ((chunk ^ (q & 7)) << 3) + (key0 & 7);
                *reinterpret_cast<unsigned*>(Pw + addr) = pk.u;
            }
        }

    // ---- O = P·V : M=queries, N=d(32), K=keys(64)
    floatx4 Oc[4][2] = {};
#pragma unroll
    for (int kc = 0; kc < 2; ++kc) {
        bf16x8 pa[4], vb[2];
#pragma unroll
        for (int mt = 0; mt < 4; ++mt) {
            int row = mt * 16 + lane15;
            pa[mt] = *reinterpret_cast<const bf16x8*>(
                Pw + row * 64 + (((kc * 4 + g4) ^ (row & 7)) << 3));
        }
#pragma unroll
        for (int n2 = 0; n2 < 2; ++n2) {
            int d = n2 * 16 + lane15;
            vb[n2] = *reinterpret_cast<const bf16x8*>(
                Vw + d * 64 + (((kc * 4 + g4) ^ (d & 7)) << 3));
        }
#pragma unroll
        for (int mt = 0; mt < 4; ++mt)
#pragma unroll
            for (int n2 = 0; n2 < 2; ++n2)
                Oc[mt][n2] = __builtin_amdgcn_mfma_f32_16x16x32_bf16(
                    pa[mt], vb[n2], Oc[mt][n2], 0, 0, 0);
    }

    // ---- store O rows < 49
#pragma unroll
    for (int mt = 0; mt < 4; ++mt)
#pragma unroll
        for (int r = 0; r < 4; ++r) {
            int query = mt * 16 + g4 * 4 + r;
            if (query < NTOK) {
                __hip_bfloat16* op = o + ((size_t)b_ * NTOK + query) * CDIM + h * DH;
#pragma unroll
                for (int n2 = 0; n2 < 2; ++n2)
                    op[n2 * 16 + lane15] = __float2bfloat16(Oc[mt][n2][r]);
            }
        }
}

// ---------------------------------------------------------------------------
extern "C" void kernel_launch(void* const* d_in, const int* in_sizes, int n_in,
                              void* d_out, int out_size, void* d_ws, size_t ws_size,
                              hipStream_t stream)
{
    const float* x        = (const float*)d_in[0];
    const float* qkv_w    = (const float*)d_in[1];
    const float* qkv_b    = (const float*)d_in[2];
    const float* rpb_tab  = (const float*)d_in[3];
    const float* proj_w   = (const float*)d_in[4];
    const float* proj_b   = (const float*)d_in[5];
    const float* n1g      = (const float*)d_in[6];
    const float* n1b      = (const float*)d_in[7];
    const float* n2g      = (const float*)d_in[8];
    const float* n2b      = (const float*)d_in[9];
    const float* fc1_w    = (const float*)d_in[10];
    const float* fc1_b    = (const float*)d_in[11];
    const float* fc2_w    = (const float*)d_in[12];
    const float* fc2_b    = (const float*)d_in[13];
    const float* sal_fg   = (const float*)d_in[15];

    char* ws = (char*)d_ws;
    __hip_bfloat16* regA = (__hip_bfloat16*)ws;
    __hip_bfloat16* regB = (__hip_bfloat16*)(ws + 205520896);
    float*          x2   = (float*)(ws + 205520896 + 51380224);
    __hip_bfloat16* wbf  = (__hip_bfloat16*)(ws + 205520896 + 51380224 + 102760448);
    __hip_bfloat16* wqkv  = wbf;
    __hip_bfloat16* wproj = wbf + 196608;
    __hip_bfloat16* wfc1  = wbf + 262144;
    __hip_bfloat16* wfc2  = wbf + 524288;

    convert_weights_kernel<<<3072, 256, 0, stream>>>(qkv_w, proj_w, fc1_w, fc2_w, wbf);

    ln_kernel<true><<<MROWS / 4, 256, 0, stream>>>(x, n1g, n1b, regB);

    gemm_kernel<0><<<dim3(768 / 128, MROWS / 128), 256, 0, stream>>>(
        regB, wqkv, qkv_b, regA, nullptr, MROWS, 768, 256);

    attn_kernel<<<2048 * 2, 256, 0, stream>>>(regA, rpb_tab, sal_fg, regB);

    gemm_kernel<1><<<dim3(256 / 128, MROWS / 128), 256, 0, stream>>>(
        regB, wproj, proj_b, x2, x, MROWS, 256, 256);

    ln_kernel<false><<<MROWS / 4, 256, 0, stream>>>(x2, n2g, n2b, regB);

    gemm_kernel<2><<<dim3(1024 / 128, MROWS / 128), 256, 0, stream>>>(
        regB, wfc1, fc1_b, regA, nullptr, MROWS, 1024, 256);

    gemm_kernel<3><<<dim3(256 / 128, MROWS / 128), 256, 0, stream>>>(
        regA, wfc2, fc2_b, d_out, x2, MROWS, 256, 1024);
}

// Round 5
// 721.339 us; speedup vs baseline: 9.4473x; 1.0901x over previous
//
#include <hip/hip_runtime.h>
#include <hip/hip_bf16.h>

// Problem constants
#define HH 56
#define WWD 56
#define WIN 7
#define SHIFT 3
#define HEADS 8
#define NTOK 49        // WIN*WIN
#define NW 64          // (56/7)^2
#define CDIM 256
#define DH 32          // CDIM/HEADS
#define MROWS 100352   // B*nW*NTOK = 2048*49
#define SCALE_Q 0.17677669529663687f

typedef float floatx4 __attribute__((ext_vector_type(4)));
typedef __bf16 bf16x8 __attribute__((ext_vector_type(8)));

__device__ __forceinline__ float wave_sum(float v) {
#pragma unroll
    for (int m = 1; m < 64; m <<= 1) v += __shfl_xor(v, m);
    return v;
}

__device__ __forceinline__ void glds16(const void* g, void* l) {
    __builtin_amdgcn_global_load_lds(
        (const __attribute__((address_space(1))) void*)g,
        (__attribute__((address_space(3))) void*)l, 16, 0, 0);
}

// ---------------------------------------------------------------------------
// Weight fp32 -> bf16 conversion
__global__ __launch_bounds__(256) void convert_weights_kernel(
    const float* __restrict__ qkv_w, const float* __restrict__ proj_w,
    const float* __restrict__ fc1_w, const float* __restrict__ fc2_w,
    __hip_bfloat16* __restrict__ dst)
{
    int i = blockIdx.x * 256 + threadIdx.x;
    float v;
    if (i < 196608)       v = qkv_w[i];
    else if (i < 262144)  v = proj_w[i - 196608];
    else if (i < 524288)  v = fc1_w[i - 262144];
    else                  v = fc2_w[i - 524288];
    dst[i] = __float2bfloat16(v);
}

// ---------------------------------------------------------------------------
// LayerNorm; SHIFTED=true also applies roll(-3,-3) + window partition scatter.
template <bool SHIFTED>
__global__ __launch_bounds__(256) void ln_kernel(
    const float* __restrict__ x, const float* __restrict__ g,
    const float* __restrict__ bb, __hip_bfloat16* __restrict__ out)
{
    const int tok  = blockIdx.x * 4 + (threadIdx.x >> 6);
    const int lane = threadIdx.x & 63;
    const int c    = lane * 4;

    float4 v = *reinterpret_cast<const float4*>(x + (size_t)tok * CDIM + c);
    float s = v.x + v.y + v.z + v.w;
    s = wave_sum(s);
    const float mean = s * (1.0f / 256.0f);
    float d0 = v.x - mean, d1 = v.y - mean, d2 = v.z - mean, d3 = v.w - mean;
    float sq = d0 * d0 + d1 * d1 + d2 * d2 + d3 * d3;
    sq = wave_sum(sq);
    const float rstd = rsqrtf(sq * (1.0f / 256.0f) + 1e-5f);

    float4 gv = *reinterpret_cast<const float4*>(g + c);
    float4 bv = *reinterpret_cast<const float4*>(bb + c);

    union { __hip_bfloat16 h[4]; uint2 u; } pk;
    pk.h[0] = __float2bfloat16(d0 * rstd * gv.x + bv.x);
    pk.h[1] = __float2bfloat16(d1 * rstd * gv.y + bv.y);
    pk.h[2] = __float2bfloat16(d2 * rstd * gv.z + bv.z);
    pk.h[3] = __float2bfloat16(d3 * rstd * gv.w + bv.w);

    size_t oidx;
    if (SHIFTED) {
        int b = tok / 3136;
        int l = tok - b * 3136;
        int h = l / WWD, w = l - (l / WWD) * WWD;
        int hp = h - SHIFT; if (hp < 0) hp += HH;
        int wp = w - SHIFT; if (wp < 0) wp += WWD;
        int bwin = b * NW + (hp / WIN) * 8 + (wp / WIN);
        int n = (hp % WIN) * WIN + (wp % WIN);
        oidx = ((size_t)bwin * NTOK + n) * CDIM + c;
    } else {
        oidx = (size_t)tok * CDIM + c;
    }
    *reinterpret_cast<uint2*>(out + oidx) = pk.u;
}

// ---------------------------------------------------------------------------
// bf16 MFMA GEMM (m97 structure): 128x128 tile, BK=32, global_load_lds(16B),
// XOR-swizzled LDS chunks. 4 waves x (64x64 via 4x4 mfma_16x16x32_bf16).
template <int MODE>
__global__ __launch_bounds__(256) void gemm_kernel(
    const __hip_bfloat16* __restrict__ A,
    const __hip_bfloat16* __restrict__ Wt,
    const float* __restrict__ bias,
    void* __restrict__ outv,
    const float* __restrict__ aux,
    int M, int Nn, int K)
{
    __shared__ __hip_bfloat16 As[128 * 32];
    __shared__ __hip_bfloat16 Bs[128 * 32];

    const int t = threadIdx.x;
    const int wave = t >> 6, lane = t & 63;
    const int m0 = blockIdx.y * 128, n0 = blockIdx.x * 128;
    const int wr = (wave >> 1) * 64;
    const int wc = (wave & 1) * 64;

    floatx4 acc[4][4] = {};

    const int c0 = wave * 64 + lane;
    const int c1 = 256 + c0;
    const int r0 = c0 >> 2, p0 = c0 & 3, g0 = p0 ^ ((r0 >> 1) & 3);
    const int r1 = c1 >> 2, p1 = c1 & 3, g1 = p1 ^ ((r1 >> 1) & 3);
    const __hip_bfloat16* gA0 = A  + (size_t)(m0 + r0) * K + g0 * 8;
    const __hip_bfloat16* gA1 = A  + (size_t)(m0 + r1) * K + g1 * 8;
    const __hip_bfloat16* gB0 = Wt + (size_t)(n0 + r0) * K + g0 * 8;
    const __hip_bfloat16* gB1 = Wt + (size_t)(n0 + r1) * K + g1 * 8;
    const int base0 = (wave * 64) * 8;
    const int base1 = (256 + wave * 64) * 8;

    const int fm = lane & 15;
    const int g4 = lane >> 4;

    for (int k0 = 0; k0 < K; k0 += 32) {
        __syncthreads();
        glds16(gA0 + k0, As + base0);
        glds16(gA1 + k0, As + base1);
        glds16(gB0 + k0, Bs + base0);
        glds16(gB1 + k0, Bs + base1);
        __syncthreads();

        bf16x8 af[4], bfr[4];
#pragma unroll
        for (int mt = 0; mt < 4; ++mt) {
            const int ml = wr + mt * 16 + fm;
            af[mt] = *reinterpret_cast<const bf16x8*>(
                As + ml * 32 + ((g4 ^ ((ml >> 1) & 3)) * 8));
            const int nl = wc + mt * 16 + fm;
            bfr[mt] = *reinterpret_cast<const bf16x8*>(
                Bs + nl * 32 + ((g4 ^ ((nl >> 1) & 3)) * 8));
        }
#pragma unroll
        for (int mt = 0; mt < 4; ++mt)
#pragma unroll
            for (int nt = 0; nt < 4; ++nt)
                acc[mt][nt] = __builtin_amdgcn_mfma_f32_16x16x32_bf16(
                    af[mt], bfr[nt], acc[mt][nt], 0, 0, 0);
    }

    float bv[4];
#pragma unroll
    for (int nt = 0; nt < 4; ++nt) bv[nt] = bias[n0 + wc + nt * 16 + fm];

#pragma unroll
    for (int mt = 0; mt < 4; ++mt) {
#pragma unroll
        for (int r = 0; r < 4; ++r) {
            const int m_g = m0 + wr + mt * 16 + g4 * 4 + r;
            size_t row_idx = 0;
            if (MODE == 1) {
                int bwin = m_g / NTOK;
                int ntok = m_g - bwin * NTOK;
                int b = bwin >> 6, wi = bwin & 63;
                int rr = ntok / WIN, cc = ntok - rr * WIN;
                int hp = (wi >> 3) * WIN + rr;
                int wp = (wi & 7) * WIN + cc;
                int h = hp + SHIFT; if (h >= HH) h -= HH;
                int w = wp + SHIFT; if (w >= WWD) w -= WWD;
                row_idx = ((size_t)b * 3136 + h * WWD + w) * CDIM;
            }
#pragma unroll
            for (int nt = 0; nt < 4; ++nt) {
                const int n_g = n0 + wc + nt * 16 + fm;
                float val = acc[mt][nt][r] + bv[nt];
                if (MODE == 0) {
                    if (n_g < 256) val *= SCALE_Q;
                    reinterpret_cast<__hip_bfloat16*>(outv)[(size_t)m_g * Nn + n_g] =
                        __float2bfloat16(val);
                } else if (MODE == 2) {
                    float gl = 0.5f * val * (1.0f + erff(val * 0.70710678118654752f));
                    reinterpret_cast<__hip_bfloat16*>(outv)[(size_t)m_g * Nn + n_g] =
                        __float2bfloat16(gl);
                } else if (MODE == 3) {
                    size_t idx = (size_t)m_g * CDIM + n_g;
                    reinterpret_cast<float*>(outv)[idx] = aux[idx] + val;
                } else {
                    size_t idx = row_idx + n_g;
                    reinterpret_cast<float*>(outv)[idx] = aux[idx] + val;
                }
            }
        }
    }
}

// ---------------------------------------------------------------------------
// Attention v5 (MFMA + cheap 3-softmax): one wave per (window, head).
// S^T = K·Q^T (16 MFMAs). Class-separated softmax: e = exp(s - m_class),
// p = e * C_class(query) — exact, overflow-safe, 64+24 exps/lane (was 384).
// V^T LDS stride 72 (4-way store conflicts, was 32-way). P LDS phase-split
// over key halves (40-ushort rows): 41.7 KB/block total.
__global__ __launch_bounds__(256) void attn_kernel(
    const __hip_bfloat16* __restrict__ qkv,   // (B_,49,768) bf16, q pre-scaled
    const float* __restrict__ rpb_table,      // (169,8)
    const float* __restrict__ sal_fg,         // (B_,49,49): row 0 = key mask
    __hip_bfloat16* __restrict__ o)           // (B_,49,256)
{
    __shared__ unsigned short Pl[4][64 * 40];   // [query][keyHalf] bf16
    __shared__ unsigned short Vt[4][32 * 72];   // [d][key] bf16, stride 72
    __shared__ float rpb_l[4][176];

    const int t = threadIdx.x;
    const int wave = t >> 6, lane = t & 63;
    const int lane15 = lane & 15, g4 = lane >> 4;
    const int b_ = blockIdx.x >> 1;
    const int h = ((blockIdx.x & 1) << 2) | wave;

    unsigned short* Pw = Pl[wave];
    unsigned short* Vw = Vt[wave];
    float* rpbw = rpb_l[wave];

    const unsigned short* qkv_u = reinterpret_cast<const unsigned short*>(qkv);
    const size_t base = (size_t)b_ * (NTOK * 768) + h * DH;

    // ---- stage V^T [d][key] stride 72; pad keys 49..63 zeroed
#pragma unroll
    for (int it = 0; it < 32; ++it) {
        int idx = it * 64 + lane;            // 2048 = 64 keys x 32 d
        int key = idx >> 5, d = idx & 31;
        unsigned short v = (key < NTOK) ? qkv_u[base + key * 768 + 512 + d]
                                        : (unsigned short)0;
        Vw[d * 72 + key] = v;
    }
#pragma unroll
    for (int it = 0; it < 3; ++it) {
        int i = it * 64 + lane;
        if (i < 169) rpbw[i] = rpb_table[i * 8 + h];
    }
    float sfv = (lane < NTOK) ? sal_fg[(size_t)b_ * (NTOK * NTOK) + lane] : -100.f;
    const unsigned long long fgmask = __ballot(sfv == 0.0f);

    // ---- K,Q fragments straight from global (16B/lane, aligned)
    bf16x8 kf[4], qf[4];
#pragma unroll
    for (int mt = 0; mt < 4; ++mt)
        kf[mt] = *reinterpret_cast<const bf16x8*>(
            qkv_u + base + (size_t)(mt * 16 + lane15) * 768 + 256 + g4 * 8);
#pragma unroll
    for (int nt = 0; nt < 4; ++nt)
        qf[nt] = *reinterpret_cast<const bf16x8*>(
            qkv_u + base + (size_t)(nt * 16 + lane15) * 768 + g4 * 8);

    // ---- S^T[key][query] = K·Q^T
    floatx4 S[4][4] = {};
#pragma unroll
    for (int mt = 0; mt < 4; ++mt)
#pragma unroll
        for (int nt = 0; nt < 4; ++nt)
            S[mt][nt] = __builtin_amdgcn_mfma_f32_16x16x32_bf16(
                kf[mt], qf[nt], S[mt][nt], 0, 0, 0);

    // ---- per-query-column constants
    const int wr_ = (b_ & 63) >> 3, wc_ = (b_ & 63) & 7;
    int qlin[4], qreg[4];
#pragma unroll
    for (int nt = 0; nt < 4; ++nt) {
        int q = nt * 16 + lane15;
        int qr = (q * 147) >> 10, qc = q - qr * 7;
        qlin[nt] = q + 6 * qr + 84;          // qr*13+qc+84
        qreg[nt] = ((wr_ == 7) ? ((qr < 4) ? 1 : 2) : 0) * 3
                 + ((wc_ == 7) ? ((qc < 4) ? 1 : 2) : 0);
    }

    // ---- apply rpb + shift-region mask; pad keys -> -1e30
#pragma unroll
    for (int mt = 0; mt < 4; ++mt)
#pragma unroll
        for (int r = 0; r < 4; ++r) {
            int key = mt * 16 + g4 * 4 + r;
            int kr = (key * 147) >> 10, kc = key - kr * 7;
            int klin = key + 6 * kr;
            int kreg = ((wr_ == 7) ? ((kr < 4) ? 1 : 2) : 0) * 3
                     + ((wc_ == 7) ? ((kc < 4) ? 1 : 2) : 0);
            bool pad = key >= NTOK;
#pragma unroll
            for (int nt = 0; nt < 4; ++nt) {
                int idx = qlin[nt] - klin;
                idx = idx < 0 ? 0 : (idx > 168 ? 168 : idx);
                float s = S[mt][nt][r] + rpbw[idx]
                        + ((qreg[nt] == kreg) ? 0.f : -100.f);
                S[mt][nt][r] = pad ? -1e30f : s;
            }
        }

    // ---- class-separated softmax stats; e = exp(s - m_class) in place
    float Cfg[4], Cbg[4];
#pragma unroll
    for (int nt = 0; nt < 4; ++nt) {
        float mfg = -3e38f, mbg = -3e38f;
#pragma unroll
        for (int mt = 0; mt < 4; ++mt)
#pragma unroll
            for (int r = 0; r < 4; ++r) {
                int key = mt * 16 + g4 * 4 + r;
                bool fg = (fgmask >> key) & 1ULL;
                float s = S[mt][nt][r];
                mfg = fg ? fmaxf(mfg, s) : mfg;
                mbg = fg ? mbg : fmaxf(mbg, s);
            }
        mfg = fmaxf(mfg, __shfl_xor(mfg, 16)); mfg = fmaxf(mfg, __shfl_xor(mfg, 32));
        mbg = fmaxf(mbg, __shfl_xor(mbg, 16)); mbg = fmaxf(mbg, __shfl_xor(mbg, 32));
        float t1 = 0.f, t2 = 0.f;
#pragma unroll
        for (int mt = 0; mt < 4; ++mt)
#pragma unroll
            for (int r = 0; r < 4; ++r) {
                int key = mt * 16 + g4 * 4 + r;
                bool fg = (fgmask >> key) & 1ULL;
                float e = __expf(S[mt][nt][r] - (fg ? mfg : mbg));
                S[mt][nt][r] = e;
                t1 += fg ? e : 0.f;
                t2 += fg ? 0.f : e;
            }
        t1 += __shfl_xor(t1, 16); t1 += __shfl_xor(t1, 32);
        t2 += __shfl_xor(t2, 16); t2 += __shfl_xor(t2, 32);
        const float m0 = fmaxf(mfg, mbg);
        const float m1 = fmaxf(mfg, mbg - 100.f);
        const float m2 = fmaxf(mfg - 100.f, mbg);
        const float a1 = __expf(mfg - m0),          a2 = __expf(mbg - m0);
        const float b1 = __expf(mfg - m1),          b2 = __expf(mbg - 100.f - m1);
        const float c1 = __expf(mfg - 100.f - m2),  c2 = __expf(mbg - m2);
        const float r0 = 1.f / (t1 * a1 + t2 * a2);
        const float r1 = 1.f / (t1 * b1 + t2 * b2);
        const float r2 = 1.f / (t1 * c1 + t2 * c2);
        Cfg[nt] = a1 * r0 + b1 * r1 - c1 * r2;
        Cbg[nt] = a2 * r0 + b2 * r1 - c2 * r2;
    }

    // ---- P write + PV, phase-split over key halves (wave-local LDS)
    floatx4 Oc[4][2] = {};
#pragma unroll
    for (int kc = 0; kc < 2; ++kc) {
#pragma unroll
        for (int mh = 0; mh < 2; ++mh) {
            const int mt = kc * 2 + mh;
#pragma unroll
            for (int rp = 0; rp < 2; ++rp) {
                const int key0 = mt * 16 + g4 * 4 + 2 * rp;
                const bool fg0 = (fgmask >> key0) & 1ULL;
                const bool fg1 = (fgmask >> (key0 + 1)) & 1ULL;
                const int keyLocal = key0 - kc * 32;
#pragma unroll
                for (int nt = 0; nt < 4; ++nt) {
                    float pA = S[mt][nt][2 * rp]     * (fg0 ? Cfg[nt] : Cbg[nt]);
                    float pB = S[mt][nt][2 * rp + 1] * (fg1 ? Cfg[nt] : Cbg[nt]);
                    union { __hip_bfloat16 hh[2]; unsigned u; } pk;
                    pk.hh[0] = __float2bfloat16(pA);
                    pk.hh[1] = __float2bfloat16(pB);
                    const int q = nt * 16 + lane15;
                    *reinterpret_cast<unsigned*>(Pw + q * 40 + keyLocal) = pk.u;
                }
            }
        }
        bf16x8 pa[4], vb[2];
#pragma unroll
        for (int mtile = 0; mtile < 4; ++mtile)
            pa[mtile] = *reinterpret_cast<const bf16x8*>(
                Pw + (mtile * 16 + lane15) * 40 + g4 * 8);
#pragma unroll
        for (int n2 = 0; n2 < 2; ++n2)
            vb[n2] = *reinterpret_cast<const bf16x8*>(
                Vw + (n2 * 16 + lane15) * 72 + kc * 32 + g4 * 8);
#pragma unroll
        for (int mtile = 0; mtile < 4; ++mtile)
#pragma unroll
            for (int n2 = 0; n2 < 2; ++n2)
                Oc[mtile][n2] = __builtin_amdgcn_mfma_f32_16x16x32_bf16(
                    pa[mtile], vb[n2], Oc[mtile][n2], 0, 0, 0);
    }

    // ---- store O rows < 49
#pragma unroll
    for (int mt = 0; mt < 4; ++mt)
#pragma unroll
        for (int r = 0; r < 4; ++r) {
            int query = mt * 16 + g4 * 4 + r;
            if (query < NTOK) {
                __hip_bfloat16* op = o + ((size_t)b_ * NTOK + query) * CDIM + h * DH;
#pragma unroll
                for (int n2 = 0; n2 < 2; ++n2)
                    op[n2 * 16 + lane15] = __float2bfloat16(Oc[mt][n2][r]);
            }
        }
}

// ---------------------------------------------------------------------------
extern "C" void kernel_launch(void* const* d_in, const int* in_sizes, int n_in,
                              void* d_out, int out_size, void* d_ws, size_t ws_size,
                              hipStream_t stream)
{
    const float* x        = (const float*)d_in[0];
    const float* qkv_w    = (const float*)d_in[1];
    const float* qkv_b    = (const float*)d_in[2];
    const float* rpb_tab  = (const float*)d_in[3];
    const float* proj_w   = (const float*)d_in[4];
    const float* proj_b   = (const float*)d_in[5];
    const float* n1g      = (const float*)d_in[6];
    const float* n1b      = (const float*)d_in[7];
    const float* n2g      = (const float*)d_in[8];
    const float* n2b      = (const float*)d_in[9];
    const float* fc1_w    = (const float*)d_in[10];
    const float* fc1_b    = (const float*)d_in[11];
    const float* fc2_w    = (const float*)d_in[12];
    const float* fc2_b    = (const float*)d_in[13];
    const float* sal_fg   = (const float*)d_in[15];

    char* ws = (char*)d_ws;
    __hip_bfloat16* regA = (__hip_bfloat16*)ws;
    __hip_bfloat16* regB = (__hip_bfloat16*)(ws + 205520896);
    float*          x2   = (float*)(ws + 205520896 + 51380224);
    __hip_bfloat16* wbf  = (__hip_bfloat16*)(ws + 205520896 + 51380224 + 102760448);
    __hip_bfloat16* wqkv  = wbf;
    __hip_bfloat16* wproj = wbf + 196608;
    __hip_bfloat16* wfc1  = wbf + 262144;
    __hip_bfloat16* wfc2  = wbf + 524288;

    convert_weights_kernel<<<3072, 256, 0, stream>>>(qkv_w, proj_w, fc1_w, fc2_w, wbf);

    ln_kernel<true><<<MROWS / 4, 256, 0, stream>>>(x, n1g, n1b, regB);

    gemm_kernel<0><<<dim3(768 / 128, MROWS / 128), 256, 0, stream>>>(
        regB, wqkv, qkv_b, regA, nullptr, MROWS, 768, 256);

    attn_kernel<<<2048 * 2, 256, 0, stream>>>(regA, rpb_tab, sal_fg, regB);

    gemm_kernel<1><<<dim3(256 / 128, MROWS / 128), 256, 0, stream>>>(
        regB, wproj, proj_b, x2, x, MROWS, 256, 256);

    ln_kernel<false><<<MROWS / 4, 256, 0, stream>>>(x2, n2g, n2b, regB);

    gemm_kernel<2><<<dim3(1024 / 128, MROWS / 128), 256, 0, stream>>>(
        regB, wfc1, fc1_b, regA, nullptr, MROWS, 1024, 256);

    gemm_kernel<3><<<dim3(256 / 128, MROWS / 128), 256, 0, stream>>>(
        regA, wfc2, fc2_b, d_out, x2, MROWS, 256, 1024);
}